// Round 12
// baseline (78.426 us; speedup 1.0000x reference)
//
#include <hip/hip_runtime.h>
#include <hip/hip_bf16.h>

#define N_TOK 4096
#define CT 256

typedef __attribute__((ext_vector_type(8))) short bf16x8;
typedef __attribute__((ext_vector_type(16))) float f32x16;

__device__ __forceinline__ unsigned pkbf(float a, float b) {
  float2 t; t.x = a; t.y = b;
  __hip_bfloat162 h = __float22bfloat162_rn(t);
  return *reinterpret_cast<unsigned*>(&h);
}

#if __has_builtin(__builtin_amdgcn_exp2f)
__device__ __forceinline__ float fexp2(float x) { return __builtin_amdgcn_exp2f(x); }
#else
__device__ __forceinline__ float fexp2(float x) { return exp2f(x); }
#endif

// ---------------------------------------------------------------------------
// prep: [0,128) X convert+transpose, [128,224) weight cvt, [224,240) gate.
// (unchanged from R5/R11)
// ---------------------------------------------------------------------------
__global__ __launch_bounds__(256) void prep_kernel(
    const float* __restrict__ thermal, const float* __restrict__ optical,
    const float* __restrict__ Wq, const float* __restrict__ Wk,
    const float* __restrict__ Wv, const float* __restrict__ Wp,
    const float* __restrict__ em, const float* __restrict__ w1,
    const float* __restrict__ b1, const float* __restrict__ w2,
    const float* __restrict__ b2,
    unsigned short* __restrict__ Xbt, unsigned short* __restrict__ Xbo,
    unsigned short* __restrict__ Wall, float* __restrict__ g)
{
  __shared__ unsigned short tile[64][264];
  const int bx = blockIdx.x, tid = threadIdx.x;
  if (bx < 128) {
    const bool th = (bx < 64);
    const float* X = th ? thermal : optical;
    unsigned short* Xb = th ? Xbt : Xbo;
    const int CIN = th ? 256 : 128;
    const int n0 = (th ? bx : bx - 64) * 64;
    const int nl = tid & 63;
    const int cw = (tid >> 6) * 4;
    for (int c0 = 0; c0 < CIN; c0 += 16) {
      int c = c0 + cw;
      float x0 = X[(size_t)(c + 0) * N_TOK + n0 + nl];
      float x1 = X[(size_t)(c + 1) * N_TOK + n0 + nl];
      float x2 = X[(size_t)(c + 2) * N_TOK + n0 + nl];
      float x3 = X[(size_t)(c + 3) * N_TOK + n0 + nl];
      uint2 w; w.x = pkbf(x0, x1); w.y = pkbf(x2, x3);
      *(uint2*)&tile[nl][c] = w;
    }
    __syncthreads();
    const int n = tid >> 2, q = tid & 3;
    const int cb = q * (CIN / 4);
    for (int j = 0; j < CIN / 4; j += 4)
      *(uint2*)(Xb + (size_t)(n0 + n) * CIN + cb + j) = *(const uint2*)&tile[n][cb + j];
  } else if (bx < 224) {
    int i = (bx - 128) * 2048 + tid * 8;   // 196608 total
    const float* src; int off;
    if (i < 65536)       { src = Wq; off = 0; }
    else if (i < 98304)  { src = Wk; off = 65536; }
    else if (i < 131072) { src = Wv; off = 98304; }
    else                 { src = Wp; off = 131072; }
    float4 f0 = *(const float4*)(src + (i - off));
    float4 f1 = *(const float4*)(src + (i - off) + 4);
    uint4 o;
    o.x = pkbf(f0.x, f0.y); o.y = pkbf(f0.z, f0.w);
    o.z = pkbf(f1.x, f1.y); o.w = pkbf(f1.z, f1.w);
    *(uint4*)(Wall + i) = o;
  } else {
    int n = (bx - 224) * 256 + tid;
    int y = n >> 6, x = n & 63;
    float e[9];
#pragma unroll
    for (int dy = 0; dy < 3; dy++)
#pragma unroll
      for (int dx = 0; dx < 3; dx++) {
        int yy = y + dy - 1, xx = x + dx - 1;
        e[dy * 3 + dx] = (yy >= 0 && yy < 64 && xx >= 0 && xx < 64)
                             ? em[yy * 64 + xx] : 0.f;
      }
    float c1[32];
#pragma unroll
    for (int oc = 0; oc < 32; oc++) {
      float a = b1[oc];
#pragma unroll
      for (int t = 0; t < 9; t++) a = fmaf(e[t], w1[oc * 9 + t], a);
      c1[oc] = fmaxf(a, 0.f);
    }
#pragma unroll
    for (int hh = 0; hh < 8; hh++) {
      float a = b2[hh];
#pragma unroll
      for (int oc = 0; oc < 32; oc++) a = fmaf(c1[oc], w2[hh * 32 + oc], a);
      g[hh * N_TOK + n] = 1.f / (1.f + __expf(-a));
    }
  }
}

// ---------------------------------------------------------------------------
// Shared 32tok x 32out MFMA tile (bf16 A/B pointers).
// ---------------------------------------------------------------------------
template <int CIN>
__device__ __forceinline__ void gemm_tile(
    const unsigned short* __restrict__ xp, const unsigned short* __restrict__ wp,
    f32x16& accE, f32x16& accO)
{
#pragma unroll
  for (int c = 0; c < CIN; c += 32) {
    bf16x8 a0 = *(const bf16x8*)(xp + c);
    bf16x8 b0 = *(const bf16x8*)(wp + c);
    bf16x8 a1 = *(const bf16x8*)(xp + c + 16);
    bf16x8 b1 = *(const bf16x8*)(wp + c + 16);
    accE = __builtin_amdgcn_mfma_f32_32x32x16_bf16(a0, b0, accE, 0, 0, 0);
    accO = __builtin_amdgcn_mfma_f32_32x32x16_bf16(a1, b1, accO, 0, 0, 0);
  }
}

// ---------------------------------------------------------------------------
// Fused QKV projection (unchanged). grid (32, 24).
// ---------------------------------------------------------------------------
__global__ __launch_bounds__(256) void qkv_kernel(
    const unsigned short* __restrict__ Xbt, const unsigned short* __restrict__ Xbo,
    const unsigned short* __restrict__ Wall,
    const float* __restrict__ bq, const float* __restrict__ bk,
    const float* __restrict__ bv, const float* __restrict__ g,
    unsigned short* __restrict__ Qh, unsigned short* __restrict__ Kh,
    unsigned short* __restrict__ Vf)
{
  __shared__ float ldsT[4][32][33];
  const int tid = threadIdx.x;
  const int wave = tid >> 6, lane = tid & 63;
  const int l31 = lane & 31, hi = lane >> 5;
  const int y = blockIdx.y;
  const int head = y & 7;
  const int n0 = blockIdx.x * 128 + wave * 32;

  f32x16 accE, accO;
#pragma unroll
  for (int i = 0; i < 16; i++) { accE[i] = 0.f; accO[i] = 0.f; }
  float bo;
  if (y < 8) {
    gemm_tile<256>(Xbt + (size_t)(n0 + l31) * 256 + hi * 8,
                   Wall + (size_t)(head * 32 + l31) * 256 + hi * 8, accE, accO);
    bo = bq[head * 32 + l31];
  } else if (y < 16) {
    gemm_tile<128>(Xbo + (size_t)(n0 + l31) * 128 + hi * 8,
                   Wall + 65536 + (size_t)(head * 32 + l31) * 128 + hi * 8, accE, accO);
    bo = bk[head * 32 + l31];
  } else {
    gemm_tile<128>(Xbo + (size_t)(n0 + l31) * 128 + hi * 8,
                   Wall + 98304 + (size_t)(head * 32 + l31) * 128 + hi * 8, accE, accO);
    bo = bv[head * 32 + l31];
  }
  float val[16];
#pragma unroll
  for (int r = 0; r < 16; r++) val[r] = accE[r] + accO[r] + bo;

  if (y < 8) {
    const float QSC = 0.17677669529663689f * 1.4426950408889634f;
#pragma unroll
    for (int r = 0; r < 16; r++) {
      int t = n0 + (r & 3) + 8 * (r >> 2) + 4 * hi;
      val[r] *= QSC * g[head * N_TOK + t];
    }
  }
#pragma unroll
  for (int r = 0; r < 16; r++)
    ldsT[wave][(r & 3) + 8 * (r >> 2) + 4 * hi][l31] = val[r];

  if (y < 16) {
    unsigned pk[8];
#pragma unroll
    for (int i = 0; i < 8; i++)
      pk[i] = pkbf(ldsT[wave][l31][16 * hi + 2 * i],
                   ldsT[wave][l31][16 * hi + 2 * i + 1]);
    unsigned short* dst = (y < 8 ? Qh : Kh) +
        ((size_t)head * N_TOK + n0 + l31) * 32 + 16 * hi;
    *(uint4*)dst = make_uint4(pk[0], pk[1], pk[2], pk[3]);
    *(uint4*)(dst + 8) = make_uint4(pk[4], pk[5], pk[6], pk[7]);
  } else {
    unsigned pk[8];
#pragma unroll
    for (int i = 0; i < 8; i++)
      pk[i] = pkbf(ldsT[wave][16 * hi + 2 * i][l31],
                   ldsT[wave][16 * hi + 2 * i + 1][l31]);
    unsigned short* dst = Vf +
        (((size_t)head * 256 + (n0 >> 4) + hi) * 32 + l31) * 16;
    *(uint4*)dst = make_uint4(pk[0], pk[1], pk[2], pk[3]);
    *(uint4*)(dst + 8) = make_uint4(pk[4], pk[5], pk[6], pk[7]);
  }
}

// ---------------------------------------------------------------------------
// Flash attention, TWO-LEVEL K-split. Grid (1024, 2): x = (head, 32-row qb),
// y = K-half. Block: 4 waves x 512 keys (same proven tile body), in-block
// LDS combine -> UNNORMALIZED f32 partial O to Abf[split] + row-sums to
// Lb[split]. 2048 blocks = 8/CU -> ~5 waves/SIMD (VGPR-limited), double the
// latency-hiding of R11's grid-capped 1024.
// ---------------------------------------------------------------------------
__global__ __launch_bounds__(256, 4) void attn_kernel(
    const unsigned short* __restrict__ Qh, const unsigned short* __restrict__ Kh,
    const unsigned short* __restrict__ Vf,
    float* __restrict__ Abf, float* __restrict__ Lb)
{
  __shared__ float combA[4][32][33];
  __shared__ float combL[4][32];
  const int tid = threadIdx.x;
  const int wave = tid >> 6, lane = tid & 63;
  const int l31 = lane & 31, hi = lane >> 5;
  const int hh = blockIdx.x >> 7;
  const int qb = blockIdx.x & 127;
  const int split = blockIdx.y;
  const int qrow0 = qb * 32;
  const int kbase0 = split * 2048 + wave * 512;

  const unsigned short* qrow = Qh + ((size_t)hh * N_TOK + qrow0 + l31) * 32;
  const bf16x8 qf0 = *(const bf16x8*)(qrow + hi * 8);
  const bf16x8 qf1 = *(const bf16x8*)(qrow + 16 + hi * 8);

  const unsigned short* kb_base = Kh + (size_t)hh * (N_TOK * 32);
  const unsigned short* vf_base = Vf + (size_t)hh * (256 * 32 * 16);

  f32x16 acc, zero16;
#pragma unroll
  for (int i = 0; i < 16; i++) { acc[i] = 0.f; zero16[i] = 0.f; }
  float lsum = 0.f;

#define LK(kb, s) (*(const bf16x8*)(kb_base + (size_t)((kb) + l31) * 32 + (s) * 16 + hi * 8))
#define LV(kt2)   (*(const bf16x8*)(vf_base + (size_t)((kt2) * 32 + l31) * 16 + hi * 8))

  bf16x8 kf0 = LK(kbase0, 0), kf1 = LK(kbase0, 1);
  bf16x8 vb0 = LV(kbase0 >> 4), vb1 = LV((kbase0 >> 4) + 1);

#pragma unroll 2
  for (int kt = 0; kt < 512; kt += 32) {
    const int nxt = (kt + 32 < 512) ? (kbase0 + kt + 32) : kbase0;
    bf16x8 nk0 = LK(nxt, 0), nk1 = LK(nxt, 1);
    bf16x8 nv0 = LV(nxt >> 4), nv1 = LV((nxt >> 4) + 1);

    f32x16 s = __builtin_amdgcn_mfma_f32_32x32x16_bf16(kf0, qf0, zero16, 0, 0, 0);
    s = __builtin_amdgcn_mfma_f32_32x32x16_bf16(kf1, qf1, s, 0, 0, 0);

    float p[16];
#pragma unroll
    for (int r = 0; r < 16; r++) p[r] = fexp2(s[r]);

    lsum += (((p[0] + p[1]) + (p[2] + p[3])) + ((p[4] + p[5]) + (p[6] + p[7]))) +
            (((p[8] + p[9]) + (p[10] + p[11])) + ((p[12] + p[13]) + (p[14] + p[15])));

    unsigned a0 = pkbf(p[0], p[1]),   a1 = pkbf(p[2], p[3]);
    unsigned b0 = pkbf(p[4], p[5]),   b1 = pkbf(p[6], p[7]);
    unsigned c0 = pkbf(p[8], p[9]),   c1 = pkbf(p[10], p[11]);
    unsigned d0 = pkbf(p[12], p[13]), d1 = pkbf(p[14], p[15]);
    asm("v_permlane32_swap_b32 %0, %1" : "+v"(a0), "+v"(b0));
    asm("v_permlane32_swap_b32 %0, %1" : "+v"(a1), "+v"(b1));
    asm("v_permlane32_swap_b32 %0, %1" : "+v"(c0), "+v"(d0));
    asm("v_permlane32_swap_b32 %0, %1" : "+v"(c1), "+v"(d1));
    union { unsigned w[4]; bf16x8 v; } u0, u1;
    u0.w[0] = a0; u0.w[1] = a1; u0.w[2] = b0; u0.w[3] = b1;
    u1.w[0] = c0; u1.w[1] = c1; u1.w[2] = d0; u1.w[3] = d1;

    acc = __builtin_amdgcn_mfma_f32_32x32x16_bf16(u0.v, vb0, acc, 0, 0, 0);
    acc = __builtin_amdgcn_mfma_f32_32x32x16_bf16(u1.v, vb1, acc, 0, 0, 0);

    kf0 = nk0; kf1 = nk1; vb0 = nv0; vb1 = nv1;
  }
#undef LK
#undef LV

  float lt = lsum + __shfl_xor(lsum, 32);
  if (hi == 0) combL[wave][l31] = lt;

#pragma unroll
  for (int r = 0; r < 16; r++)
    combA[wave][(r & 3) + 8 * (r >> 2) + 4 * hi][l31] = acc[r];
  __syncthreads();

  // combine 4 waves -> unnormalized f32 partial for this split
  const int t = tid >> 3;                  // token 0..31
  const int c4 = (tid & 7) * 4;            // vch group
  float o[4];
#pragma unroll
  for (int j = 0; j < 4; j++)
    o[j] = combA[0][t][c4 + j] + combA[1][t][c4 + j] +
           combA[2][t][c4 + j] + combA[3][t][c4 + j];
  *(float4*)(Abf + ((size_t)split * N_TOK + qrow0 + t) * CT + hh * 32 + c4) =
      make_float4(o[0], o[1], o[2], o[3]);
  if ((tid & 7) == 0) {
    float l = combL[0][t] + combL[1][t] + combL[2][t] + combL[3][t];
    Lb[((size_t)split * 8 + hh) * N_TOK + qrow0 + t] = l;
  }
}

// ---------------------------------------------------------------------------
// Output projection with fused split-combine + normalize + bf16 cvt on the
// A-fragment load. grid (32, 8).
// ---------------------------------------------------------------------------
__global__ __launch_bounds__(256) void pout_kernel(
    const float* __restrict__ Abf, const float* __restrict__ Lb,
    const unsigned short* __restrict__ Wall, const float* __restrict__ bp,
    float* __restrict__ out)
{
  const int tid = threadIdx.x;
  const int wave = tid >> 6, lane = tid & 63;
  const int l31 = lane & 31, hi = lane >> 5;
  const int n0 = blockIdx.x * 128 + wave * 32;
  const int o0 = blockIdx.y * 32;
  const int token = n0 + l31;

  float invl[8];
#pragma unroll
  for (int h = 0; h < 8; h++)
    invl[h] = 1.f / (Lb[(size_t)h * N_TOK + token] +
                     Lb[(size_t)(8 + h) * N_TOK + token]);

  const float* A0 = Abf + (size_t)token * CT;
  const float* A1 = Abf + (size_t)(N_TOK + token) * CT;

  f32x16 accE, accO;
#pragma unroll
  for (int i = 0; i < 16; i++) { accE[i] = 0.f; accO[i] = 0.f; }
  const unsigned short* wp = Wall + 131072 + (size_t)(o0 + l31) * 256 + hi * 8;

#pragma unroll
  for (int c = 0; c < 256; c += 32) {
    const float il = invl[c >> 5];
    // fragment a0: channels c+hi*8 .. +7 ; a1: c+16+hi*8 .. +7
    float4 x0a = *(const float4*)(A0 + c + hi * 8);
    float4 x0b = *(const float4*)(A0 + c + hi * 8 + 4);
    float4 y0a = *(const float4*)(A1 + c + hi * 8);
    float4 y0b = *(const float4*)(A1 + c + hi * 8 + 4);
    float4 x1a = *(const float4*)(A0 + c + 16 + hi * 8);
    float4 x1b = *(const float4*)(A0 + c + 16 + hi * 8 + 4);
    float4 y1a = *(const float4*)(A1 + c + 16 + hi * 8);
    float4 y1b = *(const float4*)(A1 + c + 16 + hi * 8 + 4);
    union { unsigned w[4]; bf16x8 v; } a0u, a1u;
    a0u.w[0] = pkbf((x0a.x + y0a.x) * il, (x0a.y + y0a.y) * il);
    a0u.w[1] = pkbf((x0a.z + y0a.z) * il, (x0a.w + y0a.w) * il);
    a0u.w[2] = pkbf((x0b.x + y0b.x) * il, (x0b.y + y0b.y) * il);
    a0u.w[3] = pkbf((x0b.z + y0b.z) * il, (x0b.w + y0b.w) * il);
    a1u.w[0] = pkbf((x1a.x + y1a.x) * il, (x1a.y + y1a.y) * il);
    a1u.w[1] = pkbf((x1a.z + y1a.z) * il, (x1a.w + y1a.w) * il);
    a1u.w[2] = pkbf((x1b.x + y1b.x) * il, (x1b.y + y1b.y) * il);
    a1u.w[3] = pkbf((x1b.z + y1b.z) * il, (x1b.w + y1b.w) * il);
    bf16x8 b0 = *(const bf16x8*)(wp + c);
    bf16x8 b1 = *(const bf16x8*)(wp + c + 16);
    accE = __builtin_amdgcn_mfma_f32_32x32x16_bf16(a0u.v, b0, accE, 0, 0, 0);
    accO = __builtin_amdgcn_mfma_f32_32x32x16_bf16(a1u.v, b1, accO, 0, 0, 0);
  }
  const float bo = bp[o0 + l31];
#pragma unroll
  for (int rr = 0; rr < 4; rr++) {
    float4 w = make_float4(accE[4 * rr + 0] + accO[4 * rr + 0] + bo,
                           accE[4 * rr + 1] + accO[4 * rr + 1] + bo,
                           accE[4 * rr + 2] + accO[4 * rr + 2] + bo,
                           accE[4 * rr + 3] + accO[4 * rr + 3] + bo);
    *(float4*)(out + (size_t)(o0 + l31) * N_TOK + n0 + 8 * rr + 4 * hi) = w;
  }
}

// ---------------------------------------------------------------------------
extern "C" void kernel_launch(void* const* d_in, const int* in_sizes, int n_in,
                              void* d_out, int out_size, void* d_ws, size_t ws_size,
                              hipStream_t stream)
{
  const float* thermal = (const float*)d_in[0];
  const float* optical = (const float*)d_in[1];
  const float* em      = (const float*)d_in[2];
  const float* Wq = (const float*)d_in[3];
  const float* bq = (const float*)d_in[4];
  const float* Wk = (const float*)d_in[5];
  const float* bk = (const float*)d_in[6];
  const float* Wv = (const float*)d_in[7];
  const float* bv = (const float*)d_in[8];
  const float* w1 = (const float*)d_in[9];
  const float* b1 = (const float*)d_in[10];
  const float* w2 = (const float*)d_in[11];
  const float* b2 = (const float*)d_in[12];
  const float* Wp = (const float*)d_in[13];
  const float* bp = (const float*)d_in[14];

  char* ws = (char*)d_ws;
  const size_t MB = 1u << 20;
  unsigned short* Xbt = (unsigned short*)(ws);                  // 2MB
  unsigned short* Xbo = (unsigned short*)(ws + 2 * MB);         // 1MB
  unsigned short* Wall = (unsigned short*)(ws + 3 * MB);        // 384KB
  float* gbuf = (float*)(ws + 3 * MB + 512 * 1024);             // 128KB
  unsigned short* Qh = (unsigned short*)(ws + 4 * MB);          // 2MB
  unsigned short* Kh = (unsigned short*)(ws + 6 * MB);          // 2MB
  unsigned short* Vf = (unsigned short*)(ws + 8 * MB);          // 2MB
  float* Abf = (float*)(ws + 10 * MB);                          // 8MB [2][4096][256]
  float* Lb  = (float*)(ws + 18 * MB);                          // 256KB [2][8][4096]

  prep_kernel<<<240, 256, 0, stream>>>(thermal, optical, Wq, Wk, Wv, Wp,
                                       em, w1, b1, w2, b2, Xbt, Xbo, Wall, gbuf);
  qkv_kernel<<<dim3(32, 24), 256, 0, stream>>>(Xbt, Xbo, Wall, bq, bk, bv, gbuf,
                                               Qh, Kh, Vf);
  attn_kernel<<<dim3(1024, 2), 256, 0, stream>>>(Qh, Kh, Vf, Abf, Lb);
  pout_kernel<<<dim3(32, 8), 256, 0, stream>>>(Abf, Lb, Wall, bp, (float*)d_out);
}

// Round 13
// 60.292 us; speedup vs baseline: 1.3008x; 1.3008x over previous
//
#include <hip/hip_runtime.h>
#include <hip/hip_bf16.h>

#define N_TOK 4096
#define CT 256

typedef __attribute__((ext_vector_type(8))) short bf16x8;
typedef __attribute__((ext_vector_type(16))) float f32x16;

__device__ __forceinline__ unsigned pkbf(float a, float b) {
  float2 t; t.x = a; t.y = b;
  __hip_bfloat162 h = __float22bfloat162_rn(t);
  return *reinterpret_cast<unsigned*>(&h);
}

#if __has_builtin(__builtin_amdgcn_exp2f)
__device__ __forceinline__ float fexp2(float x) { return __builtin_amdgcn_exp2f(x); }
#else
__device__ __forceinline__ float fexp2(float x) { return exp2f(x); }
#endif

// ---------------------------------------------------------------------------
// prep: [0,128) X convert+transpose (thermal/optical), [128,224) weight cvt,
// [224,240) emissivity gate.  (byte-identical to R11)
// ---------------------------------------------------------------------------
__global__ __launch_bounds__(256) void prep_kernel(
    const float* __restrict__ thermal, const float* __restrict__ optical,
    const float* __restrict__ Wq, const float* __restrict__ Wk,
    const float* __restrict__ Wv, const float* __restrict__ Wp,
    const float* __restrict__ em, const float* __restrict__ w1,
    const float* __restrict__ b1, const float* __restrict__ w2,
    const float* __restrict__ b2,
    unsigned short* __restrict__ Xbt, unsigned short* __restrict__ Xbo,
    unsigned short* __restrict__ Wall, float* __restrict__ g)
{
  __shared__ unsigned short tile[64][264];
  const int bx = blockIdx.x, tid = threadIdx.x;
  if (bx < 128) {
    const bool th = (bx < 64);
    const float* X = th ? thermal : optical;
    unsigned short* Xb = th ? Xbt : Xbo;
    const int CIN = th ? 256 : 128;
    const int n0 = (th ? bx : bx - 64) * 64;
    const int nl = tid & 63;
    const int cw = (tid >> 6) * 4;
    for (int c0 = 0; c0 < CIN; c0 += 16) {
      int c = c0 + cw;
      float x0 = X[(size_t)(c + 0) * N_TOK + n0 + nl];
      float x1 = X[(size_t)(c + 1) * N_TOK + n0 + nl];
      float x2 = X[(size_t)(c + 2) * N_TOK + n0 + nl];
      float x3 = X[(size_t)(c + 3) * N_TOK + n0 + nl];
      uint2 w; w.x = pkbf(x0, x1); w.y = pkbf(x2, x3);
      *(uint2*)&tile[nl][c] = w;
    }
    __syncthreads();
    const int n = tid >> 2, q = tid & 3;
    const int cb = q * (CIN / 4);
    for (int j = 0; j < CIN / 4; j += 4)
      *(uint2*)(Xb + (size_t)(n0 + n) * CIN + cb + j) = *(const uint2*)&tile[n][cb + j];
  } else if (bx < 224) {
    int i = (bx - 128) * 2048 + tid * 8;   // 196608 total
    const float* src; int off;
    if (i < 65536)       { src = Wq; off = 0; }
    else if (i < 98304)  { src = Wk; off = 65536; }
    else if (i < 131072) { src = Wv; off = 98304; }
    else                 { src = Wp; off = 131072; }
    float4 f0 = *(const float4*)(src + (i - off));
    float4 f1 = *(const float4*)(src + (i - off) + 4);
    uint4 o;
    o.x = pkbf(f0.x, f0.y); o.y = pkbf(f0.z, f0.w);
    o.z = pkbf(f1.x, f1.y); o.w = pkbf(f1.z, f1.w);
    *(uint4*)(Wall + i) = o;
  } else {
    int n = (bx - 224) * 256 + tid;
    int y = n >> 6, x = n & 63;
    float e[9];
#pragma unroll
    for (int dy = 0; dy < 3; dy++)
#pragma unroll
      for (int dx = 0; dx < 3; dx++) {
        int yy = y + dy - 1, xx = x + dx - 1;
        e[dy * 3 + dx] = (yy >= 0 && yy < 64 && xx >= 0 && xx < 64)
                             ? em[yy * 64 + xx] : 0.f;
      }
    float c1[32];
#pragma unroll
    for (int oc = 0; oc < 32; oc++) {
      float a = b1[oc];
#pragma unroll
      for (int t = 0; t < 9; t++) a = fmaf(e[t], w1[oc * 9 + t], a);
      c1[oc] = fmaxf(a, 0.f);
    }
#pragma unroll
    for (int hh = 0; hh < 8; hh++) {
      float a = b2[hh];
#pragma unroll
      for (int oc = 0; oc < 32; oc++) a = fmaf(c1[oc], w2[hh * 32 + oc], a);
      g[hh * N_TOK + n] = 1.f / (1.f + __expf(-a));
    }
  }
}

// ---------------------------------------------------------------------------
// Shared 32tok x 32out MFMA tile.
// ---------------------------------------------------------------------------
template <int CIN>
__device__ __forceinline__ void gemm_tile(
    const unsigned short* __restrict__ xp, const unsigned short* __restrict__ wp,
    f32x16& accE, f32x16& accO)
{
#pragma unroll
  for (int c = 0; c < CIN; c += 32) {
    bf16x8 a0 = *(const bf16x8*)(xp + c);
    bf16x8 b0 = *(const bf16x8*)(wp + c);
    bf16x8 a1 = *(const bf16x8*)(xp + c + 16);
    bf16x8 b1 = *(const bf16x8*)(wp + c + 16);
    accE = __builtin_amdgcn_mfma_f32_32x32x16_bf16(a0, b0, accE, 0, 0, 0);
    accO = __builtin_amdgcn_mfma_f32_32x32x16_bf16(a1, b1, accO, 0, 0, 0);
  }
}

// ---------------------------------------------------------------------------
// Fused QKV projection (byte-identical to R11). grid (32, 24).
// ---------------------------------------------------------------------------
__global__ __launch_bounds__(256) void qkv_kernel(
    const unsigned short* __restrict__ Xbt, const unsigned short* __restrict__ Xbo,
    const unsigned short* __restrict__ Wall,
    const float* __restrict__ bq, const float* __restrict__ bk,
    const float* __restrict__ bv, const float* __restrict__ g,
    unsigned short* __restrict__ Qh, unsigned short* __restrict__ Kh,
    unsigned short* __restrict__ Vf)
{
  __shared__ float ldsT[4][32][33];
  const int tid = threadIdx.x;
  const int wave = tid >> 6, lane = tid & 63;
  const int l31 = lane & 31, hi = lane >> 5;
  const int y = blockIdx.y;
  const int head = y & 7;
  const int n0 = blockIdx.x * 128 + wave * 32;

  f32x16 accE, accO;
#pragma unroll
  for (int i = 0; i < 16; i++) { accE[i] = 0.f; accO[i] = 0.f; }
  float bo;
  if (y < 8) {
    gemm_tile<256>(Xbt + (size_t)(n0 + l31) * 256 + hi * 8,
                   Wall + (size_t)(head * 32 + l31) * 256 + hi * 8, accE, accO);
    bo = bq[head * 32 + l31];
  } else if (y < 16) {
    gemm_tile<128>(Xbo + (size_t)(n0 + l31) * 128 + hi * 8,
                   Wall + 65536 + (size_t)(head * 32 + l31) * 128 + hi * 8, accE, accO);
    bo = bk[head * 32 + l31];
  } else {
    gemm_tile<128>(Xbo + (size_t)(n0 + l31) * 128 + hi * 8,
                   Wall + 98304 + (size_t)(head * 32 + l31) * 128 + hi * 8, accE, accO);
    bo = bv[head * 32 + l31];
  }
  float val[16];
#pragma unroll
  for (int r = 0; r < 16; r++) val[r] = accE[r] + accO[r] + bo;

  if (y < 8) {
    const float QSC = 0.17677669529663689f * 1.4426950408889634f;
#pragma unroll
    for (int r = 0; r < 16; r++) {
      int t = n0 + (r & 3) + 8 * (r >> 2) + 4 * hi;
      val[r] *= QSC * g[head * N_TOK + t];
    }
  }
#pragma unroll
  for (int r = 0; r < 16; r++)
    ldsT[wave][(r & 3) + 8 * (r >> 2) + 4 * hi][l31] = val[r];

  if (y < 16) {
    unsigned pk[8];
#pragma unroll
    for (int i = 0; i < 8; i++)
      pk[i] = pkbf(ldsT[wave][l31][16 * hi + 2 * i],
                   ldsT[wave][l31][16 * hi + 2 * i + 1]);
    unsigned short* dst = (y < 8 ? Qh : Kh) +
        ((size_t)head * N_TOK + n0 + l31) * 32 + 16 * hi;
    *(uint4*)dst = make_uint4(pk[0], pk[1], pk[2], pk[3]);
    *(uint4*)(dst + 8) = make_uint4(pk[4], pk[5], pk[6], pk[7]);
  } else {
    unsigned pk[8];
#pragma unroll
    for (int i = 0; i < 8; i++)
      pk[i] = pkbf(ldsT[wave][16 * hi + 2 * i][l31],
                   ldsT[wave][16 * hi + 2 * i + 1][l31]);
    unsigned short* dst = Vf +
        (((size_t)head * 256 + (n0 >> 4) + hi) * 32 + l31) * 16;
    *(uint4*)dst = make_uint4(pk[0], pk[1], pk[2], pk[3]);
    *(uint4*)(dst + 8) = make_uint4(pk[4], pk[5], pk[6], pk[7]);
  }
}

// ---------------------------------------------------------------------------
// Flash attention (R11 structure) + XCD-pinned head mapping.
// Block index: hh = bid & 7, qb = bid >> 3 -> with round-robin block->XCD
// dispatch, ALL 128 blocks of head h land on XCD h, whose K/V/Q working set
// (768 KB) is then fully resident in that XCD's private 4 MB L2 (previously
// every XCD touched all 8 heads = 6 MB > 4 MB -> thrash to L3).
// Block = 32 q-rows; 4 waves x 1024 keys; in-block combine -> bf16 Ab.
// ---------------------------------------------------------------------------
__global__ __launch_bounds__(256, 4) void attn_kernel(
    const unsigned short* __restrict__ Qh, const unsigned short* __restrict__ Kh,
    const unsigned short* __restrict__ Vf, unsigned short* __restrict__ Ab)
{
  __shared__ float combA[4][32][33];
  __shared__ float combL[4][32];
  const int tid = threadIdx.x;
  const int wave = tid >> 6, lane = tid & 63;
  const int l31 = lane & 31, hi = lane >> 5;
  const int hh = blockIdx.x & 7;          // XCD-pinned head
  const int qb = blockIdx.x >> 3;
  const int qrow0 = qb * 32;
  const int kbase0 = wave * 1024;          // per-wave key range

  const unsigned short* qrow = Qh + ((size_t)hh * N_TOK + qrow0 + l31) * 32;
  const bf16x8 qf0 = *(const bf16x8*)(qrow + hi * 8);
  const bf16x8 qf1 = *(const bf16x8*)(qrow + 16 + hi * 8);

  const unsigned short* kb_base = Kh + (size_t)hh * (N_TOK * 32);
  const unsigned short* vf_base = Vf + (size_t)hh * (256 * 32 * 16);

  f32x16 acc, zero16;
#pragma unroll
  for (int i = 0; i < 16; i++) { acc[i] = 0.f; zero16[i] = 0.f; }
  float lsum = 0.f;

#define LK(kb, s) (*(const bf16x8*)(kb_base + (size_t)((kb) + l31) * 32 + (s) * 16 + hi * 8))
#define LV(kt2)   (*(const bf16x8*)(vf_base + (size_t)((kt2) * 32 + l31) * 16 + hi * 8))

  bf16x8 kf0 = LK(kbase0, 0), kf1 = LK(kbase0, 1);
  bf16x8 vb0 = LV(kbase0 >> 4), vb1 = LV((kbase0 >> 4) + 1);

#pragma unroll 2
  for (int kt = 0; kt < 1024; kt += 32) {
    const int nxt = (kt + 32 < 1024) ? (kbase0 + kt + 32) : kbase0;
    bf16x8 nk0 = LK(nxt, 0), nk1 = LK(nxt, 1);
    bf16x8 nv0 = LV(nxt >> 4), nv1 = LV((nxt >> 4) + 1);

    f32x16 s = __builtin_amdgcn_mfma_f32_32x32x16_bf16(kf0, qf0, zero16, 0, 0, 0);
    s = __builtin_amdgcn_mfma_f32_32x32x16_bf16(kf1, qf1, s, 0, 0, 0);

    float p[16];
#pragma unroll
    for (int r = 0; r < 16; r++) p[r] = fexp2(s[r]);

    lsum += (((p[0] + p[1]) + (p[2] + p[3])) + ((p[4] + p[5]) + (p[6] + p[7]))) +
            (((p[8] + p[9]) + (p[10] + p[11])) + ((p[12] + p[13]) + (p[14] + p[15])));

    unsigned a0 = pkbf(p[0], p[1]),   a1 = pkbf(p[2], p[3]);
    unsigned b0 = pkbf(p[4], p[5]),   b1 = pkbf(p[6], p[7]);
    unsigned c0 = pkbf(p[8], p[9]),   c1 = pkbf(p[10], p[11]);
    unsigned d0 = pkbf(p[12], p[13]), d1 = pkbf(p[14], p[15]);
    asm("v_permlane32_swap_b32 %0, %1" : "+v"(a0), "+v"(b0));
    asm("v_permlane32_swap_b32 %0, %1" : "+v"(a1), "+v"(b1));
    asm("v_permlane32_swap_b32 %0, %1" : "+v"(c0), "+v"(d0));
    asm("v_permlane32_swap_b32 %0, %1" : "+v"(c1), "+v"(d1));
    union { unsigned w[4]; bf16x8 v; } u0, u1;
    u0.w[0] = a0; u0.w[1] = a1; u0.w[2] = b0; u0.w[3] = b1;
    u1.w[0] = c0; u1.w[1] = c1; u1.w[2] = d0; u1.w[3] = d1;

    acc = __builtin_amdgcn_mfma_f32_32x32x16_bf16(u0.v, vb0, acc, 0, 0, 0);
    acc = __builtin_amdgcn_mfma_f32_32x32x16_bf16(u1.v, vb1, acc, 0, 0, 0);

    kf0 = nk0; kf1 = nk1; vb0 = nv0; vb1 = nv1;
  }
#undef LK
#undef LV

  // per-wave row-sums (q-row = l31 over this wave's 1024 keys)
  float lt = lsum + __shfl_xor(lsum, 32);
  if (hi == 0) combL[wave][l31] = lt;

  // per-wave unnormalized O partials: acc[r] = O[q=crow(r,hi)][vch=l31]
#pragma unroll
  for (int r = 0; r < 16; r++)
    combA[wave][(r & 3) + 8 * (r >> 2) + 4 * hi][l31] = acc[r];
  __syncthreads();

  // combine 4 waves + normalize + write token-major bf16 Ab
  const int t = tid >> 3;                  // token 0..31
  const int c4 = (tid & 7) * 4;            // vch group
  float l = combL[0][t] + combL[1][t] + combL[2][t] + combL[3][t];
  float inv = 1.f / l;
  float o[4];
#pragma unroll
  for (int j = 0; j < 4; j++)
    o[j] = combA[0][t][c4 + j] + combA[1][t][c4 + j] +
           combA[2][t][c4 + j] + combA[3][t][c4 + j];
  uint2 pk;
  pk.x = pkbf(o[0] * inv, o[1] * inv);
  pk.y = pkbf(o[2] * inv, o[3] * inv);
  *(uint2*)(Ab + (size_t)(qrow0 + t) * CT + hh * 32 + c4) = pk;
}

// ---------------------------------------------------------------------------
// Output projection (byte-identical to R11). grid (32, 8).
// ---------------------------------------------------------------------------
__global__ __launch_bounds__(256) void pout_kernel(
    const unsigned short* __restrict__ Ab, const unsigned short* __restrict__ Wall,
    const float* __restrict__ bp, float* __restrict__ out)
{
  const int tid = threadIdx.x;
  const int wave = tid >> 6, lane = tid & 63;
  const int l31 = lane & 31, hi = lane >> 5;
  const int n0 = blockIdx.x * 128 + wave * 32;
  const int o0 = blockIdx.y * 32;

  f32x16 accE, accO;
#pragma unroll
  for (int i = 0; i < 16; i++) { accE[i] = 0.f; accO[i] = 0.f; }
  gemm_tile<256>(Ab + (size_t)(n0 + l31) * 256 + hi * 8,
                 Wall + 131072 + (size_t)(o0 + l31) * 256 + hi * 8, accE, accO);
  const float bo = bp[o0 + l31];
#pragma unroll
  for (int rr = 0; rr < 4; rr++) {
    float4 w = make_float4(accE[4 * rr + 0] + accO[4 * rr + 0] + bo,
                           accE[4 * rr + 1] + accO[4 * rr + 1] + bo,
                           accE[4 * rr + 2] + accO[4 * rr + 2] + bo,
                           accE[4 * rr + 3] + accO[4 * rr + 3] + bo);
    *(float4*)(out + (size_t)(o0 + l31) * N_TOK + n0 + 8 * rr + 4 * hi) = w;
  }
}

// ---------------------------------------------------------------------------
extern "C" void kernel_launch(void* const* d_in, const int* in_sizes, int n_in,
                              void* d_out, int out_size, void* d_ws, size_t ws_size,
                              hipStream_t stream)
{
  const float* thermal = (const float*)d_in[0];
  const float* optical = (const float*)d_in[1];
  const float* em      = (const float*)d_in[2];
  const float* Wq = (const float*)d_in[3];
  const float* bq = (const float*)d_in[4];
  const float* Wk = (const float*)d_in[5];
  const float* bk = (const float*)d_in[6];
  const float* Wv = (const float*)d_in[7];
  const float* bv = (const float*)d_in[8];
  const float* w1 = (const float*)d_in[9];
  const float* b1 = (const float*)d_in[10];
  const float* w2 = (const float*)d_in[11];
  const float* b2 = (const float*)d_in[12];
  const float* Wp = (const float*)d_in[13];
  const float* bp = (const float*)d_in[14];

  char* ws = (char*)d_ws;
  const size_t MB = 1u << 20;
  unsigned short* Xbt = (unsigned short*)(ws);                  // 2MB
  unsigned short* Xbo = (unsigned short*)(ws + 2 * MB);         // 1MB
  unsigned short* Wall = (unsigned short*)(ws + 3 * MB);        // 384KB
  float* gbuf = (float*)(ws + 3 * MB + 512 * 1024);             // 128KB
  unsigned short* Qh = (unsigned short*)(ws + 4 * MB);          // 2MB
  unsigned short* Kh = (unsigned short*)(ws + 6 * MB);          // 2MB
  unsigned short* Vf = (unsigned short*)(ws + 8 * MB);          // 2MB
  unsigned short* Ab = (unsigned short*)(ws + 10 * MB);         // 2MB

  prep_kernel<<<240, 256, 0, stream>>>(thermal, optical, Wq, Wk, Wv, Wp,
                                       em, w1, b1, w2, b2, Xbt, Xbo, Wall, gbuf);
  qkv_kernel<<<dim3(32, 24), 256, 0, stream>>>(Xbt, Xbo, Wall, bq, bk, bv, gbuf,
                                               Qh, Kh, Vf);
  attn_kernel<<<1024, 256, 0, stream>>>(Qh, Kh, Vf, Ab);
  pout_kernel<<<dim3(32, 8), 256, 0, stream>>>(Ab, Wall, bp, (float*)d_out);
}